// Round 10
// baseline (312.152 us; speedup 1.0000x reference)
//
#include <hip/hip_runtime.h>
#include <math.h>

#define NSLOTS 50
#define T 101
#define SEQ 2048
#define CHUNK 16

// v + dpp_permuted(v), pure VALU
template<int CTRL>
__device__ __forceinline__ float dpp_xadd(float v) {
    int x = __builtin_amdgcn_update_dpp(0, __float_as_int(v), CTRL, 0xF, 0xF, true);
    return v + __int_as_float(x);
}

// Full 64-lane sum -> wave-uniform scalar (validated r8/r9, absmax 0.0)
__device__ __forceinline__ float wsum64(float v) {
    v = dpp_xadd<0xB1>(v);    // xor 1
    v = dpp_xadd<0x4E>(v);    // xor 2
    v = dpp_xadd<0x141>(v);   // xor 4 (row_half_mirror)
    v = dpp_xadd<0x140>(v);   // xor 8 (row_mirror)
    v = dpp_xadd<0x142>(v);   // row_bcast15
    v = dpp_xadd<0x143>(v);   // row_bcast31
    int s = __builtin_amdgcn_readlane(__float_as_int(v), 63);
    return __int_as_float(s);
}

__device__ __forceinline__ void gl_lds(const float* g, float* lds) {
#if __has_builtin(__builtin_amdgcn_global_load_lds)
    __builtin_amdgcn_global_load_lds((const __attribute__((address_space(1))) void*)g,
        (__attribute__((address_space(3))) void*)lds, 4, 0, 0);
#else
    lds[threadIdx.x & 63] = *g;
#endif
}

__global__ __launch_bounds__(192, 1) void crf_nll_kernel(
    const float* __restrict__ feats,      // [B,S,T]
    const float* __restrict__ cdt,        // [3,5] log-probs
    const float* __restrict__ start_t,    // [T]
    const float* __restrict__ stop_t,     // [T]
    const int*   __restrict__ mask,       // [B,S]
    const int*   __restrict__ tags,       // [B,S]
    float*       __restrict__ out)        // [B]
{
    const int b = blockIdx.x, tid = threadIdx.x;
    const int wave = tid >> 6, l = tid & 63;
    const float* fb = feats + (size_t)b * SEQ * T;
    const int*   mb = mask + (size_t)b * SEQ;
    const int*   tb = tags + (size_t)b * SEQ;

    __shared__ float S[64 * 128];   // ring: step t -> slot (t-1)&63
    __shared__ float res[2];

    // ---- length (all waves; mask is a prefix of ones) ----
    float mc = 0.f;
    for (int t = l; t < SEQ; t += 64) mc += (float)mb[t];
    const int len    = (int)(wsum64(mc) + 0.5f);
    const int nsteps = len - 1;
    const int nper   = (nsteps + CHUNK - 1) / CHUNK;
    const int nfull  = nsteps / CHUNK;

    const float actm = (l < NSLOTS) ? 1.f : 0.f;
    const int aB = (2*l+1 <= 100) ? 2*l+1 : 100;
    const int aI = (2*l+2 <= 100) ? 2*l+2 : 100;
    const int s1 = (2*l+1 <= 100) ? 2*l+1 : 0;
    const int s2 = (2*l+2 <= 100) ? 2*l+2 : 0;

    const float pOO=__expf(cdt[0]),  pOB=__expf(cdt[1]),  pOI=__expf(cdt[2]);
    const float pBO=__expf(cdt[5]),  pBBs=__expf(cdt[6]), pBIs=__expf(cdt[7]),
                pBBd=__expf(cdt[8]), pBId=__expf(cdt[9]);
    const float pIO=__expf(cdt[10]), pIBs=__expf(cdt[11]), pIIs=__expf(cdt[12]),
                pIBd=__expf(cdt[13]), pIId=__expf(cdt[14]);
    const float dBB=pBBs-pBBd, dIB=pIBs-pIBd, dBI=pBIs-pBId, dII=pIIs-pIId;

    // consumer pipelined state
    float xB=0.f, xI=0.f, xO=1.f;          // lane / uniform partition (scaled)
    float XB=0.f, XI=0.f;                  // wave sums of xB,xI (scalars)
    float SB=0.f, SI=0.f;                  // in-flight weighted reductions
    float GB=0.f, GI=0.f;                  // Σ masked g (for next step's tail)
    float fB_=0.f, fI_=0.f;                // phiB(t-1), phiI(t-1)
    float gfB=0.f, gfI=0.f;                // grB(t)*phiB(t-1)
    float zB=0.f, zI=0.f;                  // egB(t)*tB(t-1)
    float egB=0.f, egI=0.f;                // raw exp g(t+1)
    float rr=1.f;                          // rescale r(t) (power of 2)
    float accF=0.f; int accE=0;
    float fOa=0.f, fOb=0.f;                // fO(t), fO(t+1)
    float gs = 0.f;                        // gold partial (wave 2)

    if (wave == 1) {
        #pragma unroll
        for (int k = 0; k < 2*CHUNK; ++k) {   // stage chunks 0,1
            const float* row = fb + (size_t)(1 + k) * T;
            float* dst = &S[(size_t)k * 128];
            gl_lds(row + s1, dst);
            gl_lds(row + s2, dst + 64);
        }
    } else if (wave == 2) {
        if (l == 0) { int tg0 = tb[0]; gs = fb[tg0] + start_t[tg0]; }
    } else {
        float pO0 = fb[0] + start_t[0];
        xB = actm * __expf(fb[aB] + start_t[aB] - pO0);
        xI = actm * __expf(fb[aI] + start_t[aI] - pO0);
        accF = pO0;
        XB = wsum64(xB); XI = wsum64(xI);
    }
    __syncthreads();   // chunks 0,1 staged

    if (wave == 0) {
        // prologue: phi(0), g(1), g(2), reductions for X(1)
        float eB0 = __builtin_fmaf(pIBd, XI, pBBd * XB);
        float eI0 = __builtin_fmaf(pIId, XI, pBId * XB);
        fB_ = pOB + eB0;                  // phiB(0)  (xO(0)=1)
        fI_ = pOI + eI0;
        float F1B = S[l],       F1I = S[64 + l],       F1O = S[50];
        float F2B = S[128 + l], F2I = S[128 + 64 + l], F2O = S[128 + 50];
        float egB1 = __expf(F1B - F1O), egI1 = __expf(F1I - F1O);
        float mgB1 = actm * egB1, mgI1 = actm * egI1;
        GB = wsum64(mgB1); GI = wsum64(mgI1);          // G(1)
        gfB = mgB1 * fB_;  gfI = mgI1 * fI_;           // r(1)=1
        float tB = __builtin_fmaf(dIB, xI, dBB * xB);
        float tI = __builtin_fmaf(dII, xI, dBI * xB);
        zB = egB1 * tB;  zI = egI1 * tI;
        SB = wsum64(zB); SI = wsum64(zI);
        egB = __expf(F2B - F2O); egI = __expf(F2I - F2O);   // g(2)
        fOa = F1O; fOb = F2O; rr = 1.f;
    }

#define STEP_BODY(GUARDED)                                                     \
    {                                                                          \
        const int t  = 1 + p * CHUNK + k;                                      \
        const int w2 = ((t + 1) & 63) << 7;   /* slot of step t+2 */           \
        float nB_ = S[w2 + l], nI_ = S[w2 + 64 + l], nO_ = S[w2 + 50];         \
        if (!(GUARDED) || t <= nsteps) {                                       \
            /* (a) lane state x(t) */                                          \
            xB = __builtin_fmaf(rr, zB, gfB);                                  \
            xI = __builtin_fmaf(rr, zI, gfI);                                  \
            /* (b) scalars at t (consume SB/SI/GB/phi(t-1)) */                 \
            float xOn = rr * __builtin_fmaf(pIO, XI,                           \
                              __builtin_fmaf(pBO, XB, pOO * xO));              \
            float XBn = rr * __builtin_fmaf(GB, fB_, SB);                      \
            float XIn = rr * __builtin_fmaf(GI, fI_, SI);                      \
            accF += fOa;                                                       \
            /* (c) eta/phi at t */                                             \
            float eBn = __builtin_fmaf(pIBd, XIn, pBBd * XBn);                 \
            float eIn = __builtin_fmaf(pIId, XIn, pBId * XBn);                 \
            fB_ = __builtin_fmaf(pOB, xOn, eBn);                               \
            fI_ = __builtin_fmaf(pOI, xOn, eIn);                               \
            /* (f) rescale r(t+1) from xO(t) exponent */                       \
            int ke = ((__float_as_int(xOn) >> 23) & 0xFF) - 127;               \
            accE += ke;                                                        \
            float rn = __int_as_float((127 - ke) << 23);                       \
            /* (e1) masked g(t+1), g*r, g*r*phi */                             \
            float mgB = actm * egB, mgI = actm * egI;                          \
            gfB = (rn * mgB) * fB_;  gfI = (rn * mgI) * fI_;                   \
            /* (d) weighted reduction toward X(t+1) */                         \
            float tB = __builtin_fmaf(dIB, xI, dBB * xB);                      \
            float tI = __builtin_fmaf(dII, xI, dBI * xB);                      \
            float zBn = egB * tB, zIn = egI * tI;                              \
            SB = wsum64(zBn); SI = wsum64(zIn);                                \
            zB = zBn; zI = zIn;                                                \
            /* (e2) G(t+1) */                                                  \
            GB = wsum64(mgB); GI = wsum64(mgI);                                \
            /* (e3) g(t+2) from just-read row */                               \
            egB = __expf(nB_ - nO_); egI = __expf(nI_ - nO_);                  \
            /* commit */                                                       \
            xO = xOn; XB = XBn; XI = XIn; rr = rn;                             \
        }                                                                      \
        fOa = fOb; fOb = nO_;                                                  \
    }

    for (int p = 0; p < nper; ++p) {
        if (wave == 0) {
            if (p < nfull) {
                #pragma unroll
                for (int k = 0; k < CHUNK; ++k) STEP_BODY(false)
            } else {
                #pragma unroll
                for (int k = 0; k < CHUNK; ++k) STEP_BODY(true)
            }
        } else if (wave == 1) {
            const int ci = p + 2;                  // stage chunk p+2
            #pragma unroll
            for (int k = 0; k < CHUNK; ++k) {
                int t = 1 + ci * CHUNK + k;
                t = (t < SEQ) ? t : (SEQ - 1);
                const float* row = fb + (size_t)t * T;
                float* dst = &S[(size_t)((ci * CHUNK + k) & 63) * 128];
                gl_lds(row + s1, dst);
                gl_lds(row + s2, dst + 64);
            }
        } else {
            // gold wave: chunk p-1 (rows live until period p+1)
            if (p >= 1 && l < CHUNK) {
                int t = 1 + (p - 1) * CHUNK + l;
                if (t <= nsteps) {
                    int tg = tb[t], tp = tb[t - 1];
                    int c1 = (tp == 0) ? 0 : ((tp & 1) ? 1 : 2);
                    int c2 = (tg == 0) ? 0 : ((tg & 1) ? 1 : 2);
                    int si = (tp - 1) >> 1, sj = (tg - 1) >> 1;
                    int t1 = (tp != 0 && si != sj) ? ((c2 == 0) ? 0 : c2 + 2) : c2;
                    gs += cdt[c1 * 5 + t1];
                    int idx = (tg == 0) ? 50 : ((tg & 1) ? ((tg - 1) >> 1) : (64 + ((tg - 2) >> 1)));
                    gs += S[(((t - 1) & 63) << 7) + idx];
                }
            }
        }
        __syncthreads();
    }
#undef STEP_BODY

    if (wave == 0) {
        // accE counted one rescale ahead: remove the never-applied last ke
        int keF = ((__float_as_int(xO) >> 23) & 0xFF) - 127;
        accE -= keF;
        float W = actm * (xB * __expf(stop_t[aB]) + xI * __expf(stop_t[aI]));
        float tot = wsum64(W) + xO * __expf(stop_t[0]);
        float fwd = accF + 0.69314718055994530942f * (float)accE + __logf(tot);
        if (l == 0) res[0] = fwd;
    } else if (wave == 2) {
        if (l < CHUNK) {   // final chunk still intact
            int t = 1 + (nper - 1) * CHUNK + l;
            if (t >= 1 && t <= nsteps) {
                int tg = tb[t], tp = tb[t - 1];
                int c1 = (tp == 0) ? 0 : ((tp & 1) ? 1 : 2);
                int c2 = (tg == 0) ? 0 : ((tg & 1) ? 1 : 2);
                int si = (tp - 1) >> 1, sj = (tg - 1) >> 1;
                int t1 = (tp != 0 && si != sj) ? ((c2 == 0) ? 0 : c2 + 2) : c2;
                gs += cdt[c1 * 5 + t1];
                int idx = (tg == 0) ? 50 : ((tg & 1) ? ((tg - 1) >> 1) : (64 + ((tg - 2) >> 1)));
                gs += S[(((t - 1) & 63) << 7) + idx];
            }
        }
        float gold = wsum64(gs);
        if (l == 0) res[1] = gold + stop_t[tb[len - 1]];
    }
    __syncthreads();
    if (tid == 0) out[b] = res[0] - res[1];
}

extern "C" void kernel_launch(void* const* d_in, const int* in_sizes, int n_in,
                              void* d_out, int out_size, void* d_ws, size_t ws_size,
                              hipStream_t stream) {
    const float* feats   = (const float*)d_in[0];
    const float* cdt     = (const float*)d_in[1];
    const float* start_t = (const float*)d_in[2];
    const float* stop_t  = (const float*)d_in[3];
    const int*   mask    = (const int*)d_in[4];
    const int*   tags    = (const int*)d_in[5];
    float* out = (float*)d_out;

    crf_nll_kernel<<<256, 192, 0, stream>>>(feats, cdt, start_t, stop_t, mask, tags, out);
}